// Round 7
// baseline (201.407 us; speedup 1.0000x reference)
//
#include <hip/hip_runtime.h>

#define NN 768
#define UU 64
#define KK 8
#define INF 136        // 2U+K
#define BB 2
#define SLOPE 0.01f
#define RECCAP 61440   // record capacity (actives ~30k)
#define NP 16          // privatized accumulator copies
#define PSTRIDE 1552   // floats per copy

__device__ __forceinline__ float lrelu(float x) { return x > 0.f ? x : SLOPE * x; }

// ---- workspace layout (bytes) ----
// s1p   : 0       (NP*PSTRIDE f32 = 99328 B)
// s2p   : 99328   (99328 B)
// gcount: 198656  (int)
// done  : 198660  (int)
// gpad  : 198664  (int)    -- memset zeroes [0, 198668)
// A     : 202752  (835584 B)
// Bv    : 1038336 (835584 B)
// recs  : 1873920 (61440 int2 = 491520 B) -> total 2365440 B

__device__ __forceinline__ float sum_copies(const float* __restrict__ sp, int bj) {
    float f = 0.f;
#pragma unroll
    for (int p = 0; p < NP; p++) f += sp[p * PSTRIDE + bj];
    return f;
}

__device__ __forceinline__ void pre_rows(int r4base, const float* __restrict__ x,
                                         const float* __restrict__ sc,
                                         const float* __restrict__ W1,
                                         float* __restrict__ A, float* __restrict__ Bv,
                                         float (*xs)[UU], int tid) {
    {
        int rr = tid >> 6, u = tid & 63;
        int bi = r4base + rr;
        float f = sc ? sum_copies(sc, bi) : 1.0f;
        xs[rr][u] = x[(size_t)bi * UU + u] * f;
    }
    __syncthreads();
    int m = tid;
    if (m < INF) {
        float a[4] = {0.f, 0.f, 0.f, 0.f}, bv[4] = {0.f, 0.f, 0.f, 0.f};
        for (int u = 0; u < UU; u++) {
            float wa = W1[u * INF + m];
            float wb = W1[(UU + u) * INF + m];
#pragma unroll
            for (int r = 0; r < 4; r++) {
                a[r]  += xs[r][u] * wa;
                bv[r] += xs[r][u] * wb;
            }
        }
#pragma unroll
        for (int r = 0; r < 4; r++) {
            A [(size_t)(r4base + r) * INF + m] = a[r];
            Bv[(size_t)(r4base + r) * INF + m] = bv[r];
        }
    }
}

// blocks [0,768): pair compaction -> int2{(i<<16|j), dinv_bits}; last block pads to mult-of-4
// blocks [768,1152): precompute hop-1 A/Bv
__global__ void __launch_bounds__(256) k_fused0(
        const float* __restrict__ rel, const float* __restrict__ seq,
        const float* __restrict__ W1, int2* __restrict__ recs,
        int* __restrict__ gcount, int* __restrict__ done, int* __restrict__ gpad,
        float* __restrict__ A, float* __restrict__ Bv) {
    __shared__ float xs[4][UU];
    __shared__ int wcnt[4];
    __shared__ int sbase;
    int blk = blockIdx.x;
    int tid = threadIdx.x;

    if (blk >= NN) {
        pre_rows((blk - NN) * 4, seq, nullptr, W1, A, Bv, xs, tid);
        return;
    }

    int i = blk;
    int w = tid >> 6, lane = tid & 63;
    int j0 = w * 192;
    float sums[3];
#pragma unroll
    for (int it = 0; it < 3; it++) {
        int j = j0 + it * 64 + lane;
        const float4* rp = (const float4*)(rel + (size_t)(i * NN + j) * KK);
        float4 a = rp[0], b = rp[1];
        sums[it] = a.x + a.y + a.z + a.w + b.x + b.y + b.z + b.w;
    }
    int cnt = 0;
    int pos[3];
    bool act[3];
#pragma unroll
    for (int it = 0; it < 3; it++) {
        act[it] = sums[it] > 0.f;
        unsigned long long m = __ballot(act[it]);
        pos[it] = cnt + __popcll(m & ((1ull << lane) - 1));
        cnt += __popcll(m);
    }
    if (lane == 0) wcnt[w] = cnt;
    __syncthreads();
    int prefix = 0, total = 0;
#pragma unroll
    for (int ww = 0; ww < 4; ww++) {
        int c = wcnt[ww];
        total += c;
        if (ww < w) prefix += c;
    }
    if (tid == 0) sbase = atomicAdd(gcount, total);
    __syncthreads();
    int base = sbase;
    float di = 1.0f / (float)total;
#pragma unroll
    for (int it = 0; it < 3; it++) {
        if (act[it]) {
            int rp = base + prefix + pos[it];
            if (rp < RECCAP)
                recs[rp] = make_int2((i << 16) | (j0 + it * 64 + lane), __float_as_int(di));
        }
    }
    // last-finishing block pads recs to a multiple of 4 with zero-weight records
    if (tid == 0) {
        __threadfence();
        int od = atomicAdd(done, 1);
        if (od == NN - 1) {
            __threadfence();
            int c = atomicAdd(gcount, 0);
            int pad = (c + 3) & ~3;
            for (int t = c; t < pad; t++) recs[t] = make_int2(0, 0); // di=0 -> contributes 0
            *gpad = pad;
        }
    }
}

// standalone precompute for hop 2 (x1 = seq * sum(s1 copies) folded in)
__global__ void __launch_bounds__(256) k_pre(const float* __restrict__ x,
                                             const float* __restrict__ sc,
                                             const float* __restrict__ W1,
                                             float* __restrict__ A, float* __restrict__ Bv) {
    __shared__ float xs[4][UU];
    pre_rows(blockIdx.x * 4, x, sc, W1, A, Bv, xs, threadIdx.x);
}

// process 2 records fully branchlessly; used in a 2-stage pipeline below
struct PairLoad {
    float4 ra, rb;
    float av[BB][3], bvv[BB][3];
    float di;
    int j;
};

__device__ __forceinline__ void load_pair(PairLoad& P, int2 rec, int lane,
                                          const float* __restrict__ A,
                                          const float* __restrict__ Bv,
                                          const float* __restrict__ rel) {
    int ij = rec.x;
    int i = ij >> 16, j = ij & 0xffff;
    P.j = j;
    P.di = __int_as_float(rec.y);
    const float* relp = rel + (size_t)(i * NN + j) * KK;
    P.ra = ((const float4*)relp)[0];
    P.rb = ((const float4*)relp)[1];
#pragma unroll
    for (int b = 0; b < BB; b++) {
        const float* Ai = A  + ((size_t)b * NN + i) * INF;
        const float* Bj = Bv + ((size_t)b * NN + j) * INF;
        P.av[b][0] = Ai[lane]; P.av[b][1] = Ai[64 + lane]; P.av[b][2] = Ai[128 + (lane & 7)];
        P.bvv[b][0] = Bj[lane]; P.bvv[b][1] = Bj[64 + lane]; P.bvv[b][2] = Bj[128 + (lane & 7)];
    }
}

__device__ __forceinline__ void compute_pair(const PairLoad& P, int lane,
                                             const float* w1r0, const float* w1r1,
                                             const float* w1r2,
                                             float b10, float b11, float b12,
                                             float w20, float w21, float w22, float b2v,
                                             float* __restrict__ s) {
    float rv[8] = {P.ra.x, P.ra.y, P.ra.z, P.ra.w, P.rb.x, P.rb.y, P.rb.z, P.rb.w};
    float r0 = b10, r1 = b11, r2 = b12;
#pragma unroll
    for (int k = 0; k < 8; k++) {
        r0 += rv[k] * w1r0[k];
        r1 += rv[k] * w1r1[k];
        r2 += rv[k] * w1r2[k];
    }
    float dd[BB];
#pragma unroll
    for (int b = 0; b < BB; b++) {
        float dot = lrelu(r0 + P.av[b][0] + P.bvv[b][0]) * w20
                  + lrelu(r1 + P.av[b][1] + P.bvv[b][1]) * w21;
        if (lane < 8)
            dot += lrelu(r2 + P.av[b][2] + P.bvv[b][2]) * w22;
#pragma unroll
        for (int off = 32; off; off >>= 1) dot += __shfl_xor(dot, off, 64);
        dd[b] = dot;
    }
    if (lane == 0)  atomicAdd(&s[P.j],      lrelu(dd[0] + b2v) * P.di);
    if (lane == 32) atomicAdd(&s[NN + P.j], lrelu(dd[1] + b2v) * P.di);
}

// one wave per 4 records: 2-stage software pipeline (load pair t+2 while computing t)
__global__ void __launch_bounds__(256, 6) k_hop(
        const int2* __restrict__ recs, const int* __restrict__ gpad,
        const float* __restrict__ A, const float* __restrict__ Bv,
        const float* __restrict__ rel, const float* __restrict__ W1,
        const float* __restrict__ b1, const float* __restrict__ w2,
        const float* __restrict__ b2, float* __restrict__ sp) {
    int lane = threadIdx.x & 63;
    int wid = (blockIdx.x * blockDim.x + threadIdx.x) >> 6;
    int p = wid * 4;
    if (p >= *gpad) return;
    float* s = sp + (wid & (NP - 1)) * PSTRIDE;

    const float* W1R = W1 + 128 * INF;
    float w1r0[8], w1r1[8], w1r2[8];
#pragma unroll
    for (int k = 0; k < 8; k++) {
        w1r0[k] = W1R[k * INF + lane];
        w1r1[k] = W1R[k * INF + 64 + lane];
        w1r2[k] = W1R[k * INF + 128 + (lane & 7)];
    }
    float b10 = b1[lane], b11 = b1[64 + lane], b12 = b1[128 + (lane & 7)];
    float w20 = w2[lane], w21 = w2[64 + lane];
    float w22 = (lane < 8) ? w2[128 + lane] : 0.f;
    float b2v = b2[0];

    int4 qa = *(const int4*)(recs + p);        // recs[p], recs[p+1]
    int4 qb = *(const int4*)(recs + p + 2);    // recs[p+2], recs[p+3]

    PairLoad P0, P1, P2, P3;
    load_pair(P0, make_int2(qa.x, qa.y), lane, A, Bv, rel);
    load_pair(P1, make_int2(qa.z, qa.w), lane, A, Bv, rel);
    load_pair(P2, make_int2(qb.x, qb.y), lane, A, Bv, rel);  // in flight during P0/P1 compute
    compute_pair(P0, lane, w1r0, w1r1, w1r2, b10, b11, b12, w20, w21, w22, b2v, s);
    load_pair(P3, make_int2(qb.z, qb.w), lane, A, Bv, rel);
    compute_pair(P1, lane, w1r0, w1r1, w1r2, b10, b11, b12, w20, w21, w22, b2v, s);
    compute_pair(P2, lane, w1r0, w1r1, w1r2, b10, b11, b12, w20, w21, w22, b2v, s);
    compute_pair(P3, lane, w1r0, w1r1, w1r2, b10, b11, b12, w20, w21, w22, b2v, s);
}

// out[b,j,u] = seq[b,j,u] * sum(s1 copies)[b,j] * sum(s2 copies)[b,j]
__global__ void __launch_bounds__(256) k_final(const float4* __restrict__ seq,
                                               const float* __restrict__ s1p,
                                               const float* __restrict__ s2p,
                                               float4* __restrict__ out) {
    int idx = blockIdx.x * blockDim.x + threadIdx.x;
    int bj = idx >> 4;
    float f = sum_copies(s1p, bj) * sum_copies(s2p, bj);
    float4 v = seq[idx];
    v.x *= f; v.y *= f; v.z *= f; v.w *= f;
    out[idx] = v;
}

extern "C" void kernel_launch(void* const* d_in, const int* in_sizes, int n_in,
                              void* d_out, int out_size, void* d_ws, size_t ws_size,
                              hipStream_t stream) {
    const float* seq = (const float*)d_in[0];   // (2,768,64)
    const float* rel = (const float*)d_in[1];   // (768,768,8)
    const float* w1_1 = (const float*)d_in[2];  // (136,136)
    const float* b1_1 = (const float*)d_in[3];
    const float* w1_2 = (const float*)d_in[4];  // (136,1)
    const float* b1_2 = (const float*)d_in[5];
    const float* w2_1 = (const float*)d_in[6];
    const float* b2_1 = (const float*)d_in[7];
    const float* w2_2 = (const float*)d_in[8];
    const float* b2_2 = (const float*)d_in[9];
    float* out = (float*)d_out;

    char* ws = (char*)d_ws;
    float* s1p    = (float*)(ws + 0);
    float* s2p    = (float*)(ws + 99328);
    int*   gcount = (int*)  (ws + 198656);
    int*   done   = (int*)  (ws + 198660);
    int*   gpad   = (int*)  (ws + 198664);
    float* A      = (float*)(ws + 202752);
    float* Bv     = (float*)(ws + 1038336);
    int2*  recs   = (int2*) (ws + 1873920);

    hipMemsetAsync(ws, 0, 198668, stream);

    k_fused0<<<NN + 384, 256, 0, stream>>>(rel, seq, w1_1, recs, gcount, done, gpad, A, Bv);

    k_hop<<<RECCAP / 16, 256, 0, stream>>>(recs, gpad, A, Bv, rel, w1_1, b1_1, w1_2, b1_2, s1p);

    k_pre<<<384, 256, 0, stream>>>(seq, s1p, w2_1, A, Bv);
    k_hop<<<RECCAP / 16, 256, 0, stream>>>(recs, gpad, A, Bv, rel, w2_1, b2_1, w2_2, b2_2, s2p);

    k_final<<<BB * NN * UU / 4 / 256, 256, 0, stream>>>((const float4*)seq, s1p, s2p, (float4*)out);
}

// Round 8
// 146.840 us; speedup vs baseline: 1.3716x; 1.3716x over previous
//
#include <hip/hip_runtime.h>

#define NN 768
#define UU 64
#define KK 8
#define INF 136        // 2U+K
#define BB 2
#define SLOPE 0.01f
#define RECCAP 61440   // record capacity (actives ~30k)
#define NP 16          // privatized accumulator copies
#define PSTRIDE 1552   // floats per copy

__device__ __forceinline__ float lrelu(float x) { return x > 0.f ? x : SLOPE * x; }

// ---- workspace layout (bytes) ----
// s1p   : 0       (NP*PSTRIDE f32 = 99328 B)
// s2p   : 99328   (99328 B)
// gcount: 198656  (int)
// done  : 198660  (int)
// gpad  : 198664  (int)    -- memset zeroes [0, 198668)
// A     : 202752  (835584 B)
// Bv    : 1038336 (835584 B)
// recs  : 1873920 (61440 int2 = 491520 B) -> total 2365440 B

__device__ __forceinline__ float sum_copies(const float* __restrict__ sp, int bj) {
    float f = 0.f;
#pragma unroll
    for (int p = 0; p < NP; p++) f += sp[p * PSTRIDE + bj];
    return f;
}

__device__ __forceinline__ void pre_rows(int r4base, const float* __restrict__ x,
                                         const float* __restrict__ sc,
                                         const float* __restrict__ W1,
                                         float* __restrict__ A, float* __restrict__ Bv,
                                         float (*xs)[UU], int tid) {
    {
        int rr = tid >> 6, u = tid & 63;
        int bi = r4base + rr;
        float f = sc ? sum_copies(sc, bi) : 1.0f;
        xs[rr][u] = x[(size_t)bi * UU + u] * f;
    }
    __syncthreads();
    int m = tid;
    if (m < INF) {
        float a[4] = {0.f, 0.f, 0.f, 0.f}, bv[4] = {0.f, 0.f, 0.f, 0.f};
        for (int u = 0; u < UU; u++) {
            float wa = W1[u * INF + m];
            float wb = W1[(UU + u) * INF + m];
#pragma unroll
            for (int r = 0; r < 4; r++) {
                a[r]  += xs[r][u] * wa;
                bv[r] += xs[r][u] * wb;
            }
        }
#pragma unroll
        for (int r = 0; r < 4; r++) {
            A [(size_t)(r4base + r) * INF + m] = a[r];
            Bv[(size_t)(r4base + r) * INF + m] = bv[r];
        }
    }
}

// blocks [0,768): pair compaction -> int2{(i<<16|j), dinv_bits}; last block pads to mult-of-32
// blocks [768,1152): precompute hop-1 A/Bv
__global__ void __launch_bounds__(256) k_fused0(
        const float* __restrict__ rel, const float* __restrict__ seq,
        const float* __restrict__ W1, int2* __restrict__ recs,
        int* __restrict__ gcount, int* __restrict__ done, int* __restrict__ gpad,
        float* __restrict__ A, float* __restrict__ Bv) {
    __shared__ float xs[4][UU];
    __shared__ int wcnt[4];
    __shared__ int sbase;
    int blk = blockIdx.x;
    int tid = threadIdx.x;

    if (blk >= NN) {
        pre_rows((blk - NN) * 4, seq, nullptr, W1, A, Bv, xs, tid);
        return;
    }

    int i = blk;
    int w = tid >> 6, lane = tid & 63;
    int j0 = w * 192;
    float sums[3];
#pragma unroll
    for (int it = 0; it < 3; it++) {
        int j = j0 + it * 64 + lane;
        const float4* rp = (const float4*)(rel + (size_t)(i * NN + j) * KK);
        float4 a = rp[0], b = rp[1];
        sums[it] = a.x + a.y + a.z + a.w + b.x + b.y + b.z + b.w;
    }
    int cnt = 0;
    int pos[3];
    bool act[3];
#pragma unroll
    for (int it = 0; it < 3; it++) {
        act[it] = sums[it] > 0.f;
        unsigned long long m = __ballot(act[it]);
        pos[it] = cnt + __popcll(m & ((1ull << lane) - 1));
        cnt += __popcll(m);
    }
    if (lane == 0) wcnt[w] = cnt;
    __syncthreads();
    int prefix = 0, total = 0;
#pragma unroll
    for (int ww = 0; ww < 4; ww++) {
        int c = wcnt[ww];
        total += c;
        if (ww < w) prefix += c;
    }
    if (tid == 0) sbase = atomicAdd(gcount, total);
    __syncthreads();
    int base = sbase;
    float di = 1.0f / (float)total;
#pragma unroll
    for (int it = 0; it < 3; it++) {
        if (act[it]) {
            int rp = base + prefix + pos[it];
            if (rp < RECCAP)
                recs[rp] = make_int2((i << 16) | (j0 + it * 64 + lane), __float_as_int(di));
        }
    }
    // last-finishing block pads recs to a multiple of 32 with zero-weight records
    if (tid == 0) {
        __threadfence();
        int od = atomicAdd(done, 1);
        if (od == NN - 1) {
            __threadfence();
            int c = atomicAdd(gcount, 0);
            int pad = (c + 31) & ~31;
            if (pad > RECCAP) pad = RECCAP;
            for (int t = c; t < pad; t++) recs[t] = make_int2(0, 0); // di=0 -> contributes 0
            *gpad = pad;
        }
    }
}

// standalone precompute for hop 2 (x1 = seq * sum(s1 copies) folded in)
__global__ void __launch_bounds__(256) k_pre(const float* __restrict__ x,
                                             const float* __restrict__ sc,
                                             const float* __restrict__ W1,
                                             float* __restrict__ A, float* __restrict__ Bv) {
    __shared__ float xs[4][UU];
    pre_rows(blockIdx.x * 4, x, sc, W1, A, Bv, xs, threadIdx.x);
}

// one wave = 8 pairs x 8 feature-phases. lane = p*8+g: pair p, features m = 8t+g (t=0..16).
// 8 pairs share one instruction stream (8-way chain overlap, no extra registers);
// dot reduce = 3 shfl steps within the 8-lane group.
__global__ void __launch_bounds__(256, 4) k_hop(
        const int2* __restrict__ recs, const int* __restrict__ gpad,
        const float* __restrict__ A, const float* __restrict__ Bv,
        const float* __restrict__ rel, const float* __restrict__ W1,
        const float* __restrict__ b1, const float* __restrict__ w2,
        const float* __restrict__ b2, float* __restrict__ sp) {
    __shared__ float W1Rs[KK * INF];
    __shared__ float b1s[INF];
    __shared__ float w2s[INF];
    {
        const float* W1R = W1 + 128 * INF;
        for (int t = threadIdx.x; t < KK * INF; t += 256) W1Rs[t] = W1R[t];
        for (int t = threadIdx.x; t < INF; t += 256) { b1s[t] = b1[t]; w2s[t] = w2[t]; }
    }
    __syncthreads();

    int lane = threadIdx.x & 63;
    int wid = (blockIdx.x * blockDim.x + threadIdx.x) >> 6;
    int base = wid * 8;
    if (base >= *gpad) return;          // gpad is a multiple of 8 (padded to 32)

    int g = lane & 7;                    // feature phase
    int p = lane >> 3;                   // pair slot 0..7
    int2 rec = recs[base + p];           // 8-way broadcast per pair group
    int ij = rec.x;
    int i = ij >> 16, j = ij & 0xffff;
    float di = __int_as_float(rec.y);
    float* s = sp + (wid & (NP - 1)) * PSTRIDE;

    const float* relp = rel + (size_t)(i * NN + j) * KK;
    float4 ra = ((const float4*)relp)[0];
    float4 rb = ((const float4*)relp)[1];
    float rv[8] = {ra.x, ra.y, ra.z, ra.w, rb.x, rb.y, rb.z, rb.w};

    const float* Ai0 = A  + (size_t)i * INF;
    const float* Ai1 = A  + (size_t)(NN + i) * INF;
    const float* Bj0 = Bv + (size_t)j * INF;
    const float* Bj1 = Bv + (size_t)(NN + j) * INF;

    float acc0 = 0.f, acc1 = 0.f;
#pragma unroll
    for (int t = 0; t < 17; t++) {
        int m = 8 * t + g;
        float r = b1s[m];
#pragma unroll
        for (int k = 0; k < 8; k++) r += rv[k] * W1Rs[k * INF + m];
        float w2v = w2s[m];
        float z0 = r + Ai0[m] + Bj0[m];
        float z1 = r + Ai1[m] + Bj1[m];
        acc0 += w2v * lrelu(z0);
        acc1 += w2v * lrelu(z1);
    }
#pragma unroll
    for (int off = 1; off <= 4; off <<= 1) {
        acc0 += __shfl_xor(acc0, off, 64);
        acc1 += __shfl_xor(acc1, off, 64);
    }
    float b2v = b2[0];
    if (g == 0) atomicAdd(&s[j],      lrelu(acc0 + b2v) * di);
    if (g == 1) atomicAdd(&s[NN + j], lrelu(acc1 + b2v) * di);
}

// out[b,j,u] = seq[b,j,u] * sum(s1 copies)[b,j] * sum(s2 copies)[b,j]
__global__ void __launch_bounds__(256) k_final(const float4* __restrict__ seq,
                                               const float* __restrict__ s1p,
                                               const float* __restrict__ s2p,
                                               float4* __restrict__ out) {
    int idx = blockIdx.x * blockDim.x + threadIdx.x;
    int bj = idx >> 4;
    float f = sum_copies(s1p, bj) * sum_copies(s2p, bj);
    float4 v = seq[idx];
    v.x *= f; v.y *= f; v.z *= f; v.w *= f;
    out[idx] = v;
}

extern "C" void kernel_launch(void* const* d_in, const int* in_sizes, int n_in,
                              void* d_out, int out_size, void* d_ws, size_t ws_size,
                              hipStream_t stream) {
    const float* seq = (const float*)d_in[0];   // (2,768,64)
    const float* rel = (const float*)d_in[1];   // (768,768,8)
    const float* w1_1 = (const float*)d_in[2];  // (136,136)
    const float* b1_1 = (const float*)d_in[3];
    const float* w1_2 = (const float*)d_in[4];  // (136,1)
    const float* b1_2 = (const float*)d_in[5];
    const float* w2_1 = (const float*)d_in[6];
    const float* b2_1 = (const float*)d_in[7];
    const float* w2_2 = (const float*)d_in[8];
    const float* b2_2 = (const float*)d_in[9];
    float* out = (float*)d_out;

    char* ws = (char*)d_ws;
    float* s1p    = (float*)(ws + 0);
    float* s2p    = (float*)(ws + 99328);
    int*   gcount = (int*)  (ws + 198656);
    int*   done   = (int*)  (ws + 198660);
    int*   gpad   = (int*)  (ws + 198664);
    float* A      = (float*)(ws + 202752);
    float* Bv     = (float*)(ws + 1038336);
    int2*  recs   = (int2*) (ws + 1873920);

    hipMemsetAsync(ws, 0, 198668, stream);

    k_fused0<<<NN + 384, 256, 0, stream>>>(rel, seq, w1_1, recs, gcount, done, gpad, A, Bv);

    k_hop<<<RECCAP / 32, 256, 0, stream>>>(recs, gpad, A, Bv, rel, w1_1, b1_1, w1_2, b1_2, s1p);

    k_pre<<<384, 256, 0, stream>>>(seq, s1p, w2_1, A, Bv);
    k_hop<<<RECCAP / 32, 256, 0, stream>>>(recs, gpad, A, Bv, rel, w2_1, b2_1, w2_2, b2_2, s2p);

    k_final<<<BB * NN * UU / 4 / 256, 256, 0, stream>>>((const float4*)seq, s1p, s2p, (float4*)out);
}